// Round 2
// baseline (219.805 us; speedup 1.0000x reference)
//
#include <hip/hip_runtime.h>

// Decorrelation (iterative whitening) normalization.
// Input:  (64, 56, 56, 256) f32, NHWC (C contiguous). N = 200704 positions.
// Groups: 16 groups x 16 channels. Newton-Schulz x5 for Sigma^{-1/2}.
//
// Lane mapping (both streaming kernels): lane handles channels [4*lane, 4*lane+4)
// => quad (4 consecutive lanes) == one 16-channel group. Cross-channel products
// within the group use DPP quad_perm broadcasts (VALU, no LDS pipe).
//
// ws float layout:
//   [0,    256)  : channel sums (atomic accum)
//   [256,  4352) : second-moment sums per group (g*256 + i*16 + j)
//   [4352, 4608) : channel means (written by k_wm)
//   [4608, 8704) : whitening matrices (g*256 + i*16 + j)

constexpr int CCH = 256;
constexpr float EPSV = 1e-3f;

// DPP quad_perm broadcast of lane (quad_base + S) within each 4-lane quad.
#define QB(S, comp) __int_as_float(__builtin_amdgcn_update_dpp( \
    0, __float_as_int(comp), (S) * 0x55, 0xF, 0xF, 1))

// Swizzled LDS cov index: <=2-way bank conflicts for the wave-wide atomics.
__device__ __forceinline__ int cidx(int g, int i, int j) {
    return g * 273 + i * 17 + j;
}

__global__ __launch_bounds__(512) void k_stats(const float* __restrict__ x,
                                               float* __restrict__ sums,
                                               float* __restrict__ covs,
                                               int npos) {
    const int tid = threadIdx.x;
    const int lane = tid & 63;
    const int wave = blockIdx.x * (blockDim.x >> 6) + (tid >> 6);
    const int nwaves = gridDim.x * (blockDim.x >> 6);

    float s4[4] = {0.f, 0.f, 0.f, 0.f};
    float cv[4][16];
#pragma unroll
    for (int a = 0; a < 4; ++a)
#pragma unroll
        for (int j = 0; j < 16; ++j) cv[a][j] = 0.f;

    const float* bx = x + lane * 4;

    int p = wave;
    if (p < npos) {
        float4 v = *reinterpret_cast<const float4*>(bx + (size_t)p * CCH);
        while (true) {
            const int pn = p + nwaves;
            const bool more = pn < npos;
            float4 vn = v;
            if (more) vn = *reinterpret_cast<const float4*>(bx + (size_t)pn * CCH);

            s4[0] += v.x; s4[1] += v.y; s4[2] += v.z; s4[3] += v.w;
            const float va[4] = {v.x, v.y, v.z, v.w};
#define STEP(S)                                                          \
            {                                                            \
                const float u0 = QB(S, v.x), u1 = QB(S, v.y),            \
                            u2 = QB(S, v.z), u3 = QB(S, v.w);            \
                _Pragma("unroll")                                        \
                for (int a = 0; a < 4; ++a) {                            \
                    cv[a][(S) * 4 + 0] += va[a] * u0;                    \
                    cv[a][(S) * 4 + 1] += va[a] * u1;                    \
                    cv[a][(S) * 4 + 2] += va[a] * u2;                    \
                    cv[a][(S) * 4 + 3] += va[a] * u3;                    \
                }                                                        \
            }
            STEP(0) STEP(1) STEP(2) STEP(3)
#undef STEP
            if (!more) break;
            p = pn;
            v = vn;
        }
    }

    // Block-level merge (swizzled LDS to avoid 64-way bank conflicts).
    __shared__ float lsum[324];    // lane*5 + a
    __shared__ float lcov[4368];   // cidx(g, i, j)
    for (int i2 = tid; i2 < 324; i2 += blockDim.x) lsum[i2] = 0.f;
    for (int i2 = tid; i2 < 4368; i2 += blockDim.x) lcov[i2] = 0.f;
    __syncthreads();

    const int g = lane >> 2;
    const int il0 = (lane & 3) * 4;
#pragma unroll
    for (int a = 0; a < 4; ++a) atomicAdd(&lsum[lane * 5 + a], s4[a]);
#pragma unroll
    for (int a = 0; a < 4; ++a)
#pragma unroll
        for (int j = 0; j < 16; ++j)
            atomicAdd(&lcov[cidx(g, il0 + a, j)], cv[a][j]);
    __syncthreads();

    for (int c = tid; c < 256; c += blockDim.x)
        atomicAdd(&sums[c], lsum[(c >> 2) * 5 + (c & 3)]);
    for (int e = tid; e < 4096; e += blockDim.x) {
        const int gg = e >> 8, r = e & 255;
        atomicAdd(&covs[e], lcov[cidx(gg, r >> 4, r & 15)]);
    }
}

// One block per group; thread (i,j) owns element (i,j) of the 16x16 matrices.
__global__ __launch_bounds__(256) void k_wm(const float* __restrict__ sums,
                                            const float* __restrict__ covs,
                                            float* __restrict__ mean,
                                            float* __restrict__ wm,
                                            float inv_n) {
    const int g = blockIdx.x;
    const int tid = threadIdx.x;
    const int i = tid >> 4;
    const int j = tid & 15;

    __shared__ float mu[16];
    __shared__ float sig[16][17];
    __shared__ float P[16][17];
    __shared__ float T[16][17];
    __shared__ float U[16][17];

    if (tid < 16) {
        float m = sums[g * 16 + tid] * inv_n;
        mu[tid] = m;
        mean[g * 16 + tid] = m;
    }
    __syncthreads();

    const float cov = covs[(g * 16 + i) * 16 + j] * inv_n - mu[i] * mu[j];
    const float s = (1.0f - EPSV) * cov + ((i == j) ? EPSV : 0.0f);
    sig[i][j] = s;
    __syncthreads();

    float tr = 0.f;
#pragma unroll
    for (int k = 0; k < 16; ++k) tr += sig[k][k];
    __syncthreads();

    sig[i][j] = s / tr;               // sigma_n
    P[i][j] = (i == j) ? 1.0f : 0.0f;
    __syncthreads();

    for (int it = 0; it < 5; ++it) {
        float a = 0.f;
#pragma unroll
        for (int k = 0; k < 16; ++k) a += P[i][k] * P[k][j];
        T[i][j] = a;
        __syncthreads();

        float b = 0.f;
#pragma unroll
        for (int k = 0; k < 16; ++k) b += T[i][k] * P[k][j];
        U[i][j] = b;
        __syncthreads();

        float c = 0.f;
#pragma unroll
        for (int k = 0; k < 16; ++k) c += U[i][k] * sig[k][j];
        const float pn = 1.5f * P[i][j] - 0.5f * c;
        __syncthreads();
        P[i][j] = pn;
        __syncthreads();
    }

    wm[(g * 16 + i) * 16 + j] = P[i][j] * rsqrtf(tr);
}

__global__ __launch_bounds__(256) void k_whiten(const float* __restrict__ x,
                                                const float* __restrict__ mean,
                                                const float* __restrict__ wm,
                                                float* __restrict__ out,
                                                int npos) {
    const int tid = threadIdx.x;
    const int lane = tid & 63;
    const int wave = blockIdx.x * (blockDim.x >> 6) + (tid >> 6);
    const int nwaves = gridDim.x * (blockDim.x >> 6);
    const int g = lane >> 2;
    const int i0 = (lane & 3) * 4;

    // Per-lane whitening rows: 4 output channels x 16 input channels.
    float w[4][16];
    const float* wg = wm + g * 256;
#pragma unroll
    for (int a = 0; a < 4; ++a)
#pragma unroll
        for (int j = 0; j < 16; ++j) w[a][j] = wg[(i0 + a) * 16 + j];

    const float4 mu4 = *reinterpret_cast<const float4*>(mean + lane * 4);
    const float* bx = x + lane * 4;
    float* bo = out + lane * 4;

    int p = wave;
    if (p >= npos) return;
    float4 v = *reinterpret_cast<const float4*>(bx + (size_t)p * CCH);
    while (true) {
        const int pn = p + nwaves;
        const bool more = pn < npos;
        float4 vn = v;
        if (more) vn = *reinterpret_cast<const float4*>(bx + (size_t)pn * CCH);

        v.x -= mu4.x; v.y -= mu4.y; v.z -= mu4.z; v.w -= mu4.w;
        float acc[4] = {0.f, 0.f, 0.f, 0.f};
#define STEP(S)                                                          \
        {                                                                \
            const float u0 = QB(S, v.x), u1 = QB(S, v.y),                \
                        u2 = QB(S, v.z), u3 = QB(S, v.w);                \
            _Pragma("unroll")                                            \
            for (int a = 0; a < 4; ++a) {                                \
                acc[a] += w[a][(S) * 4 + 0] * u0 + w[a][(S) * 4 + 1] * u1 \
                        + w[a][(S) * 4 + 2] * u2 + w[a][(S) * 4 + 3] * u3; \
            }                                                            \
        }
        STEP(0) STEP(1) STEP(2) STEP(3)
#undef STEP
        float4 o;
        o.x = acc[0]; o.y = acc[1]; o.z = acc[2]; o.w = acc[3];
        *reinterpret_cast<float4*>(bo + (size_t)p * CCH) = o;

        if (!more) break;
        p = pn;
        v = vn;
    }
}

extern "C" void kernel_launch(void* const* d_in, const int* in_sizes, int n_in,
                              void* d_out, int out_size, void* d_ws, size_t ws_size,
                              hipStream_t stream) {
    const float* x = (const float*)d_in[0];
    float* out = (float*)d_out;
    float* ws = (float*)d_ws;

    const int total = in_sizes[0];
    const int npos = total / CCH;   // 200704
    const float inv_n = 1.0f / (float)npos;

    // zero the accumulator region (sums + cov sums)
    hipMemsetAsync(d_ws, 0, 4352 * sizeof(float), stream);

    k_stats<<<512, 512, 0, stream>>>(x, ws, ws + 256, npos);
    k_wm<<<16, 256, 0, stream>>>(ws, ws + 256, ws + 4352, ws + 4608, inv_n);
    k_whiten<<<2048, 256, 0, stream>>>(x, ws + 4352, ws + 4608, out, npos);
}

// Round 3
// 202.083 us; speedup vs baseline: 1.0877x; 1.0877x over previous
//
#include <hip/hip_runtime.h>

// Decorrelation (iterative whitening) normalization.
// Input:  (64, 56, 56, 256) f32, NHWC (C contiguous). N = 200704 positions.
// Groups: 16 groups x 16 channels. Newton-Schulz x5 for Sigma^{-1/2}.
//
// Lane mapping (streaming kernels): lane handles channels [4*lane, 4*lane+4)
// => quad (4 consecutive lanes) == one 16-channel group. Cross-channel products
// within the group use DPP quad_perm broadcasts (VALU, no LDS pipe).
//
// ws float layout:
//   [0,    256)   : final channel sums (zeroed, k_reduce atomics: 8/address)
//   [256,  4352)  : final cov sums (g*256 + i*16 + j)
//   [4352, 4608)  : channel means (written by k_wm)
//   [4608, 8704)  : whitening matrices (g*256 + i*16 + j)
//   [8704, ...)   : per-block partials, NBLK x 4352 (plain coalesced stores)

constexpr int CCH = 256;
constexpr float EPSV = 1e-3f;
constexpr int NBLK = 512;       // k_stats blocks
constexpr int PSTRIDE = 4352;   // floats per partial record

// DPP quad_perm broadcast of lane (quad_base + S) within each 4-lane quad.
#define QB(S, comp) __int_as_float(__builtin_amdgcn_update_dpp( \
    0, __float_as_int(comp), (S) * 0x55, 0xF, 0xF, 1))

// Swizzled LDS cov index: <=2-way bank conflicts for the wave-wide atomics.
__device__ __forceinline__ int cidx(int g, int i, int j) {
    return g * 273 + i * 17 + j;
}

__global__ __launch_bounds__(256) void k_stats(const float* __restrict__ x,
                                               float* __restrict__ partial,
                                               int npos) {
    const int tid = threadIdx.x;
    const int lane = tid & 63;
    const int wave = blockIdx.x * (blockDim.x >> 6) + (tid >> 6);
    const int nwaves = gridDim.x * (blockDim.x >> 6);

    float s4[4] = {0.f, 0.f, 0.f, 0.f};
    float cv[4][16];
#pragma unroll
    for (int a = 0; a < 4; ++a)
#pragma unroll
        for (int j = 0; j < 16; ++j) cv[a][j] = 0.f;

    const float* bx = x + lane * 4;

    // Prefetch depth 2 for memory-level parallelism.
    int p = wave;
    if (p < npos) {
        float4 v0 = *reinterpret_cast<const float4*>(bx + (size_t)p * CCH);
        int p1 = p + nwaves;
        float4 v1 = v0;
        if (p1 < npos) v1 = *reinterpret_cast<const float4*>(bx + (size_t)p1 * CCH);
        while (true) {
            const int p2 = p + 2 * nwaves;
            const bool more2 = p2 < npos;
            float4 v2 = v0;
            if (more2) v2 = *reinterpret_cast<const float4*>(bx + (size_t)p2 * CCH);

            s4[0] += v0.x; s4[1] += v0.y; s4[2] += v0.z; s4[3] += v0.w;
            const float va[4] = {v0.x, v0.y, v0.z, v0.w};
#define STEP(S)                                                          \
            {                                                            \
                const float u0 = QB(S, v0.x), u1 = QB(S, v0.y),          \
                            u2 = QB(S, v0.z), u3 = QB(S, v0.w);          \
                _Pragma("unroll")                                        \
                for (int a = 0; a < 4; ++a) {                            \
                    cv[a][(S) * 4 + 0] += va[a] * u0;                    \
                    cv[a][(S) * 4 + 1] += va[a] * u1;                    \
                    cv[a][(S) * 4 + 2] += va[a] * u2;                    \
                    cv[a][(S) * 4 + 3] += va[a] * u3;                    \
                }                                                        \
            }
            STEP(0) STEP(1) STEP(2) STEP(3)
#undef STEP
            if (p + nwaves >= npos) break;
            p += nwaves;
            v0 = v1;
            v1 = v2;
        }
    }

    // Block-level merge (swizzled LDS to avoid 64-way bank conflicts).
    __shared__ float lsum[324];    // lane*5 + a
    __shared__ float lcov[4368];   // cidx(g, i, j)
    for (int i2 = tid; i2 < 324; i2 += blockDim.x) lsum[i2] = 0.f;
    for (int i2 = tid; i2 < 4368; i2 += blockDim.x) lcov[i2] = 0.f;
    __syncthreads();

    const int g = lane >> 2;
    const int il0 = (lane & 3) * 4;
#pragma unroll
    for (int a = 0; a < 4; ++a) atomicAdd(&lsum[lane * 5 + a], s4[a]);
#pragma unroll
    for (int a = 0; a < 4; ++a)
#pragma unroll
        for (int j = 0; j < 16; ++j)
            atomicAdd(&lcov[cidx(g, il0 + a, j)], cv[a][j]);
    __syncthreads();

    // Plain coalesced stores of this block's partial record (no atomics).
    float* rec = partial + (size_t)blockIdx.x * PSTRIDE;
    for (int c = tid; c < 256; c += blockDim.x)
        rec[c] = lsum[(c >> 2) * 5 + (c & 3)];
    for (int e = tid; e < 4096; e += blockDim.x) {
        const int gg = e >> 8, r = e & 255;
        rec[256 + e] = lcov[cidx(gg, r >> 4, r & 15)];
    }
}

// Reduce NBLK partial records into the final 4352 accumulators.
// Grid: (NBLK/64) chunks * 4352 outputs = 8*4352 threads; 8 atomics/address.
__global__ __launch_bounds__(256) void k_reduce(const float* __restrict__ partial,
                                                float* __restrict__ finalv) {
    const int t = blockIdx.x * blockDim.x + threadIdx.x;
    const int total = (NBLK / 64) * PSTRIDE;
    if (t >= total) return;
    const int chunk = t / PSTRIDE;
    const int e = t - chunk * PSTRIDE;
    const float* src = partial + (size_t)chunk * 64 * PSTRIDE + e;
    float acc = 0.f;
#pragma unroll 8
    for (int b = 0; b < 64; ++b) acc += src[(size_t)b * PSTRIDE];
    atomicAdd(&finalv[e], acc);
}

// One block per group; thread (i,j) owns element (i,j) of the 16x16 matrices.
__global__ __launch_bounds__(256) void k_wm(const float* __restrict__ sums,
                                            const float* __restrict__ covs,
                                            float* __restrict__ mean,
                                            float* __restrict__ wm,
                                            float inv_n) {
    const int g = blockIdx.x;
    const int tid = threadIdx.x;
    const int i = tid >> 4;
    const int j = tid & 15;

    __shared__ float mu[16];
    __shared__ float sig[16][17];
    __shared__ float P[16][17];
    __shared__ float T[16][17];
    __shared__ float U[16][17];

    if (tid < 16) {
        float m = sums[g * 16 + tid] * inv_n;
        mu[tid] = m;
        mean[g * 16 + tid] = m;
    }
    __syncthreads();

    const float cov = covs[(g * 16 + i) * 16 + j] * inv_n - mu[i] * mu[j];
    const float s = (1.0f - EPSV) * cov + ((i == j) ? EPSV : 0.0f);
    sig[i][j] = s;
    __syncthreads();

    float tr = 0.f;
#pragma unroll
    for (int k = 0; k < 16; ++k) tr += sig[k][k];
    __syncthreads();

    sig[i][j] = s / tr;               // sigma_n
    P[i][j] = (i == j) ? 1.0f : 0.0f;
    __syncthreads();

    for (int it = 0; it < 5; ++it) {
        float a = 0.f;
#pragma unroll
        for (int k = 0; k < 16; ++k) a += P[i][k] * P[k][j];
        T[i][j] = a;
        __syncthreads();

        float b = 0.f;
#pragma unroll
        for (int k = 0; k < 16; ++k) b += T[i][k] * P[k][j];
        U[i][j] = b;
        __syncthreads();

        float c = 0.f;
#pragma unroll
        for (int k = 0; k < 16; ++k) c += U[i][k] * sig[k][j];
        const float pn = 1.5f * P[i][j] - 0.5f * c;
        __syncthreads();
        P[i][j] = pn;
        __syncthreads();
    }

    wm[(g * 16 + i) * 16 + j] = P[i][j] * rsqrtf(tr);
}

__global__ __launch_bounds__(256) void k_whiten(const float* __restrict__ x,
                                                const float* __restrict__ mean,
                                                const float* __restrict__ wm,
                                                float* __restrict__ out,
                                                int npos) {
    const int tid = threadIdx.x;
    const int lane = tid & 63;
    const int wave = blockIdx.x * (blockDim.x >> 6) + (tid >> 6);
    const int nwaves = gridDim.x * (blockDim.x >> 6);
    const int g = lane >> 2;
    const int i0 = (lane & 3) * 4;

    // Per-lane whitening rows: 4 output channels x 16 input channels.
    float w[4][16];
    const float* wg = wm + g * 256;
#pragma unroll
    for (int a = 0; a < 4; ++a)
#pragma unroll
        for (int j = 0; j < 16; ++j) w[a][j] = wg[(i0 + a) * 16 + j];

    const float4 mu4 = *reinterpret_cast<const float4*>(mean + lane * 4);
    const float* bx = x + lane * 4;
    float* bo = out + lane * 4;

    int p = wave;
    if (p >= npos) return;
    float4 v = *reinterpret_cast<const float4*>(bx + (size_t)p * CCH);
    while (true) {
        const int pn = p + nwaves;
        const bool more = pn < npos;
        float4 vn = v;
        if (more) vn = *reinterpret_cast<const float4*>(bx + (size_t)pn * CCH);

        v.x -= mu4.x; v.y -= mu4.y; v.z -= mu4.z; v.w -= mu4.w;
        float acc[4] = {0.f, 0.f, 0.f, 0.f};
#define STEP(S)                                                          \
        {                                                                \
            const float u0 = QB(S, v.x), u1 = QB(S, v.y),                \
                        u2 = QB(S, v.z), u3 = QB(S, v.w);                \
            _Pragma("unroll")                                            \
            for (int a = 0; a < 4; ++a) {                                \
                acc[a] += w[a][(S) * 4 + 0] * u0 + w[a][(S) * 4 + 1] * u1 \
                        + w[a][(S) * 4 + 2] * u2 + w[a][(S) * 4 + 3] * u3; \
            }                                                            \
        }
        STEP(0) STEP(1) STEP(2) STEP(3)
#undef STEP
        float4 o;
        o.x = acc[0]; o.y = acc[1]; o.z = acc[2]; o.w = acc[3];
        *reinterpret_cast<float4*>(bo + (size_t)p * CCH) = o;

        if (!more) break;
        p = pn;
        v = vn;
    }
}

extern "C" void kernel_launch(void* const* d_in, const int* in_sizes, int n_in,
                              void* d_out, int out_size, void* d_ws, size_t ws_size,
                              hipStream_t stream) {
    const float* x = (const float*)d_in[0];
    float* out = (float*)d_out;
    float* ws = (float*)d_ws;

    const int total = in_sizes[0];
    const int npos = total / CCH;   // 200704
    const float inv_n = 1.0f / (float)npos;

    float* finalv = ws;            // [0,4352): sums+covs
    float* mean = ws + 4352;
    float* wm = ws + 4608;
    float* partial = ws + 8704;    // NBLK * PSTRIDE floats

    // zero only the final accumulators (k_reduce atomics land here)
    hipMemsetAsync(d_ws, 0, 4352 * sizeof(float), stream);

    k_stats<<<NBLK, 256, 0, stream>>>(x, partial, npos);
    const int rthreads = (NBLK / 64) * PSTRIDE;
    k_reduce<<<(rthreads + 255) / 256, 256, 0, stream>>>(partial, finalv);
    k_wm<<<16, 256, 0, stream>>>(finalv, finalv + 256, mean, wm, inv_n);
    k_whiten<<<2048, 256, 0, stream>>>(x, mean, wm, out, npos);
}

// Round 4
// 183.957 us; speedup vs baseline: 1.1949x; 1.0985x over previous
//
#include <hip/hip_runtime.h>

// Decorrelation (iterative whitening) normalization.
// Input:  (64, 56, 56, 256) f32, NHWC (C contiguous). N = 200704 positions.
// Groups: 16 groups x 16 channels. Newton-Schulz x5 for Sigma^{-1/2}.
//
// Lane mapping (streaming kernels): lane handles channels [4*lane, 4*lane+4)
// => quad (4 consecutive lanes) == one 16-channel group. Cross-channel products
// within the group use DPP quad_perm broadcasts (VALU, no LDS pipe).
//
// k_stats is latency-limited, not BW-limited (replays run from L3): keep 8
// loads in flight per wave via double-buffered batches of 8 float4s.
//
// ws float layout:
//   [0,    256)   : final channel sums (zeroed, k_reduce atomics: 8/address)
//   [256,  4352)  : final cov sums (g*256 + i*16 + j)
//   [4352, 4608)  : channel means (written by k_wm)
//   [4608, 8704)  : whitening matrices (g*256 + i*16 + j)
//   [8704, ...)   : per-block partials, NBLK x 4352 (plain coalesced stores)

constexpr int CCH = 256;
constexpr float EPSV = 1e-3f;
constexpr int NBLK = 512;       // k_stats blocks
constexpr int PSTRIDE = 4352;   // floats per partial record

// DPP quad_perm broadcast of lane (quad_base + S) within each 4-lane quad.
#define QB(S, comp) __int_as_float(__builtin_amdgcn_update_dpp( \
    0, __float_as_int(comp), (S) * 0x55, 0xF, 0xF, 1))

// Swizzled LDS cov index: <=2-way bank conflicts for the wave-wide atomics.
__device__ __forceinline__ int cidx(int g, int i, int j) {
    return g * 273 + i * 17 + j;
}

// Accumulate one position's 4 channels into sums + 4x16 cov slice.
#define STEPX(S, V, VA)                                                  \
    {                                                                    \
        const float u0 = QB(S, (V).x), u1 = QB(S, (V).y),                \
                    u2 = QB(S, (V).z), u3 = QB(S, (V).w);                \
        _Pragma("unroll")                                                \
        for (int a = 0; a < 4; ++a) {                                    \
            cv[a][(S) * 4 + 0] += VA[a] * u0;                            \
            cv[a][(S) * 4 + 1] += VA[a] * u1;                            \
            cv[a][(S) * 4 + 2] += VA[a] * u2;                            \
            cv[a][(S) * 4 + 3] += VA[a] * u3;                            \
        }                                                                \
    }

#define ACC1(V)                                                          \
    {                                                                    \
        s4[0] += (V).x; s4[1] += (V).y; s4[2] += (V).z; s4[3] += (V).w;  \
        const float va_[4] = {(V).x, (V).y, (V).z, (V).w};               \
        STEPX(0, V, va_) STEPX(1, V, va_) STEPX(2, V, va_)               \
        STEPX(3, V, va_)                                                 \
    }

#define LOAD8(BUF, P)                                                    \
    {                                                                    \
        _Pragma("unroll")                                                \
        for (int k_ = 0; k_ < 8; ++k_)                                   \
            BUF[k_] = *reinterpret_cast<const float4*>(                  \
                bx + (size_t)((P) + k_) * CCH);                          \
    }

#define ACC8(BUF)                                                        \
    {                                                                    \
        _Pragma("unroll")                                                \
        for (int k_ = 0; k_ < 8; ++k_) ACC1(BUF[k_])                     \
    }

__global__ __launch_bounds__(256) void k_stats(const float* __restrict__ x,
                                               float* __restrict__ partial,
                                               int npos) {
    const int tid = threadIdx.x;
    const int lane = tid & 63;
    const int wid = blockIdx.x * (blockDim.x >> 6) + (tid >> 6);
    const int nw = gridDim.x * (blockDim.x >> 6);

    float s4[4] = {0.f, 0.f, 0.f, 0.f};
    float cv[4][16];
#pragma unroll
    for (int a = 0; a < 4; ++a)
#pragma unroll
        for (int j = 0; j < 16; ++j) cv[a][j] = 0.f;

    const float* bx = x + lane * 4;

    // Contiguous chunk per wave (npos=200704, nw=2048 -> chunk=98 exact).
    const int chunk = (npos + nw - 1) / nw;
    const int start = wid * chunk;
    const int end = (start + chunk < npos) ? start + chunk : npos;
    const int n = (end > start) ? end - start : 0;
    const int nfull = n & ~7;
    const int pend = start + nfull;

    float4 A[8], B[8];
    if (nfull) {
        int p = start;
        LOAD8(A, p);
        while (true) {
            const int pn = p + 8;
            if (pn < pend) {
                LOAD8(B, pn);
                ACC8(A);
                const int pn2 = pn + 8;
                if (pn2 < pend) {
                    LOAD8(A, pn2);
                    ACC8(B);
                    p = pn2;
                } else {
                    ACC8(B);
                    break;
                }
            } else {
                ACC8(A);
                break;
            }
        }
    }
    for (int q = start + nfull; q < end; ++q) {
        const float4 v = *reinterpret_cast<const float4*>(bx + (size_t)q * CCH);
        ACC1(v);
    }

    // Block-level merge (swizzled LDS to avoid 64-way bank conflicts).
    __shared__ float lsum[324];    // lane*5 + a
    __shared__ float lcov[4368];   // cidx(g, i, j)
    for (int i2 = tid; i2 < 324; i2 += blockDim.x) lsum[i2] = 0.f;
    for (int i2 = tid; i2 < 4368; i2 += blockDim.x) lcov[i2] = 0.f;
    __syncthreads();

    const int g = lane >> 2;
    const int il0 = (lane & 3) * 4;
#pragma unroll
    for (int a = 0; a < 4; ++a) atomicAdd(&lsum[lane * 5 + a], s4[a]);
#pragma unroll
    for (int a = 0; a < 4; ++a)
#pragma unroll
        for (int j = 0; j < 16; ++j)
            atomicAdd(&lcov[cidx(g, il0 + a, j)], cv[a][j]);
    __syncthreads();

    // Plain coalesced stores of this block's partial record (no atomics).
    float* rec = partial + (size_t)blockIdx.x * PSTRIDE;
    for (int c = tid; c < 256; c += blockDim.x)
        rec[c] = lsum[(c >> 2) * 5 + (c & 3)];
    for (int e = tid; e < 4096; e += blockDim.x) {
        const int gg = e >> 8, r = e & 255;
        rec[256 + e] = lcov[cidx(gg, r >> 4, r & 15)];
    }
}

// Reduce NBLK partial records into the final 4352 accumulators.
// Grid: (NBLK/64) chunks * 4352 outputs = 8*4352 threads; 8 atomics/address.
__global__ __launch_bounds__(256) void k_reduce(const float* __restrict__ partial,
                                                float* __restrict__ finalv) {
    const int t = blockIdx.x * blockDim.x + threadIdx.x;
    const int total = (NBLK / 64) * PSTRIDE;
    if (t >= total) return;
    const int chunk = t / PSTRIDE;
    const int e = t - chunk * PSTRIDE;
    const float* src = partial + (size_t)chunk * 64 * PSTRIDE + e;
    float acc = 0.f;
#pragma unroll 8
    for (int b = 0; b < 64; ++b) acc += src[(size_t)b * PSTRIDE];
    atomicAdd(&finalv[e], acc);
}

// One block per group; thread (i,j) owns element (i,j) of the 16x16 matrices.
__global__ __launch_bounds__(256) void k_wm(const float* __restrict__ sums,
                                            const float* __restrict__ covs,
                                            float* __restrict__ mean,
                                            float* __restrict__ wm,
                                            float inv_n) {
    const int g = blockIdx.x;
    const int tid = threadIdx.x;
    const int i = tid >> 4;
    const int j = tid & 15;

    __shared__ float mu[16];
    __shared__ float sig[16][17];
    __shared__ float P[16][17];
    __shared__ float T[16][17];
    __shared__ float U[16][17];

    if (tid < 16) {
        float m = sums[g * 16 + tid] * inv_n;
        mu[tid] = m;
        mean[g * 16 + tid] = m;
    }
    __syncthreads();

    const float cov = covs[(g * 16 + i) * 16 + j] * inv_n - mu[i] * mu[j];
    const float s = (1.0f - EPSV) * cov + ((i == j) ? EPSV : 0.0f);
    sig[i][j] = s;
    __syncthreads();

    float tr = 0.f;
#pragma unroll
    for (int k = 0; k < 16; ++k) tr += sig[k][k];
    __syncthreads();

    sig[i][j] = s / tr;               // sigma_n
    P[i][j] = (i == j) ? 1.0f : 0.0f;
    __syncthreads();

    for (int it = 0; it < 5; ++it) {
        float a = 0.f;
#pragma unroll
        for (int k = 0; k < 16; ++k) a += P[i][k] * P[k][j];
        T[i][j] = a;
        __syncthreads();

        float b = 0.f;
#pragma unroll
        for (int k = 0; k < 16; ++k) b += T[i][k] * P[k][j];
        U[i][j] = b;
        __syncthreads();

        float c = 0.f;
#pragma unroll
        for (int k = 0; k < 16; ++k) c += U[i][k] * sig[k][j];
        const float pn = 1.5f * P[i][j] - 0.5f * c;
        __syncthreads();
        P[i][j] = pn;
        __syncthreads();
    }

    wm[(g * 16 + i) * 16 + j] = P[i][j] * rsqrtf(tr);
}

__global__ __launch_bounds__(256) void k_whiten(const float* __restrict__ x,
                                                const float* __restrict__ mean,
                                                const float* __restrict__ wm,
                                                float* __restrict__ out,
                                                int npos) {
    const int tid = threadIdx.x;
    const int lane = tid & 63;
    const int wave = blockIdx.x * (blockDim.x >> 6) + (tid >> 6);
    const int nwaves = gridDim.x * (blockDim.x >> 6);
    const int g = lane >> 2;
    const int i0 = (lane & 3) * 4;

    // Per-lane whitening rows: 4 output channels x 16 input channels.
    float w[4][16];
    const float* wg = wm + g * 256;
#pragma unroll
    for (int a = 0; a < 4; ++a)
#pragma unroll
        for (int j = 0; j < 16; ++j) w[a][j] = wg[(i0 + a) * 16 + j];

    const float4 mu4 = *reinterpret_cast<const float4*>(mean + lane * 4);
    const float* bx = x + lane * 4;
    float* bo = out + lane * 4;

    int p = wave;
    if (p >= npos) return;
    float4 v = *reinterpret_cast<const float4*>(bx + (size_t)p * CCH);
    while (true) {
        const int pn = p + nwaves;
        const bool more = pn < npos;
        float4 vn = v;
        if (more) vn = *reinterpret_cast<const float4*>(bx + (size_t)pn * CCH);

        v.x -= mu4.x; v.y -= mu4.y; v.z -= mu4.z; v.w -= mu4.w;
        float acc[4] = {0.f, 0.f, 0.f, 0.f};
#define WSTEP(S)                                                         \
        {                                                                \
            const float u0 = QB(S, v.x), u1 = QB(S, v.y),                \
                        u2 = QB(S, v.z), u3 = QB(S, v.w);                \
            _Pragma("unroll")                                            \
            for (int a = 0; a < 4; ++a) {                                \
                acc[a] += w[a][(S) * 4 + 0] * u0 + w[a][(S) * 4 + 1] * u1 \
                        + w[a][(S) * 4 + 2] * u2 + w[a][(S) * 4 + 3] * u3; \
            }                                                            \
        }
        WSTEP(0) WSTEP(1) WSTEP(2) WSTEP(3)
#undef WSTEP
        float4 o;
        o.x = acc[0]; o.y = acc[1]; o.z = acc[2]; o.w = acc[3];
        *reinterpret_cast<float4*>(bo + (size_t)p * CCH) = o;

        if (!more) break;
        p = pn;
        v = vn;
    }
}

extern "C" void kernel_launch(void* const* d_in, const int* in_sizes, int n_in,
                              void* d_out, int out_size, void* d_ws, size_t ws_size,
                              hipStream_t stream) {
    const float* x = (const float*)d_in[0];
    float* out = (float*)d_out;
    float* ws = (float*)d_ws;

    const int total = in_sizes[0];
    const int npos = total / CCH;   // 200704
    const float inv_n = 1.0f / (float)npos;

    float* finalv = ws;            // [0,4352): sums+covs
    float* mean = ws + 4352;
    float* wm = ws + 4608;
    float* partial = ws + 8704;    // NBLK * PSTRIDE floats

    // zero only the final accumulators (k_reduce atomics land here)
    hipMemsetAsync(d_ws, 0, 4352 * sizeof(float), stream);

    k_stats<<<NBLK, 256, 0, stream>>>(x, partial, npos);
    const int rthreads = (NBLK / 64) * PSTRIDE;
    k_reduce<<<(rthreads + 255) / 256, 256, 0, stream>>>(partial, finalv);
    k_wm<<<16, 256, 0, stream>>>(finalv, finalv + 256, mean, wm, inv_n);
    k_whiten<<<2048, 256, 0, stream>>>(x, mean, wm, out, npos);
}